// Round 5
// baseline (39.883 us; speedup 1.0000x reference)
//
#include <hip/hip_runtime.h>
#include <hip/hip_bf16.h>

#define NB 8
#define NS 256
#define NN 128
#define NC 64
#define NH 4
#define AH 128
#define HID 256
#define FH 32

typedef float f32x4 __attribute__((ext_vector_type(4)));

// ws float layout (offsets kept from prior rounds):
// [1536, 1792)   const0[o] = ffn_b[o] + sum_k ffn_w[o][k]*val_b[k]
// [1792, 2816)   W[o][h]  = sum_d ffn_w[o][h*32+d]*val_w[h*32+d]

__global__ __launch_bounds__(256) void fold_kernel(
    const float* __restrict__ val_w, const float* __restrict__ val_b,
    const float* __restrict__ ffn_w, const float* __restrict__ ffn_b,
    float* __restrict__ ws)
{
    __shared__ float sVw[AH], sVb[AH];
    const int t = threadIdx.x;
    if (t < AH) { sVw[t] = val_w[t]; sVb[t] = val_b[t]; }
    __syncthreads();

    const int o = t;  // 0..255
    const float4* fr = reinterpret_cast<const float4*>(ffn_w + o * AH);
    float c0 = ffn_b[o];
    float w[NH] = {0.f, 0.f, 0.f, 0.f};
    #pragma unroll
    for (int k4 = 0; k4 < AH / 4; ++k4) {
        const float4 f = fr[k4];
        const int k = k4 * 4;
        const int h = k >> 5;
        c0  = fmaf(f.x, sVb[k], fmaf(f.y, sVb[k+1], fmaf(f.z, sVb[k+2], fmaf(f.w, sVb[k+3], c0))));
        w[h] = fmaf(f.x, sVw[k], fmaf(f.y, sVw[k+1], fmaf(f.z, sVw[k+2], fmaf(f.w, sVw[k+3], w[h]))));
    }
    ws[1536 + o] = c0;
    *reinterpret_cast<float4*>(ws + 1792 + o * NH) = make_float4(w[0], w[1], w[2], w[3]);
}

__global__ __launch_bounds__(256) void out_kernel(
    const int* __restrict__ src,      // (B,S,N) int32, values {0,1}
    const int* __restrict__ labels,   // (B,N)
    const float* __restrict__ sp_d, const float* __restrict__ tp_d,
    const float* __restrict__ c_sp_p, const float* __restrict__ sp_w1, const float* __restrict__ sp_w2,
    const float* __restrict__ c_tp_p, const float* __restrict__ tp_w1, const float* __restrict__ tp_w2,
    const float* __restrict__ attn_w,
    const float* __restrict__ ws,
    float* __restrict__ out)          // (B,S,C,HID) float32
{
    __shared__ float sE[NN], sEx0[NN], sEx1[NN];
    __shared__ int   sLab[NN];
    __shared__ float sPa[NC][NH], sPb[NC][NH];
    __shared__ float sHm[NC];

    const int blk = blockIdx.x;      // b*128 + s_pair
    const int b  = blk >> 7;
    const int s0 = (blk & 127) * 2;
    const int t  = threadIdx.x;

    // Early fetch of per-o constants (independent of barriers below).
    const int o0 = (t & 63) * 4;     // 0..255 step 4
    const int crow = t >> 6;         // 0..3
    const f32x4 c0v = *reinterpret_cast<const f32x4*>(ws + 1536 + o0);
    f32x4 wrow[4];
    #pragma unroll
    for (int i = 0; i < 4; ++i)
        wrow[i] = *reinterpret_cast<const f32x4*>(ws + 1792 + (size_t)(o0 + i) * NH);

    // ---- FIRE bias + stage (t < 128) ----
    if (t < NN) {
        const float csp = fmaxf(c_sp_p[0], 0.0f);
        const float ctp = fmaxf(c_tp_p[0], 0.0f);
        const float dsp = sp_d[b * NN + t];
        const float dtp = tp_d[b * NN + t];
        const int   lab = labels[b * NN + t];
        const int   x0  = src[((size_t)(b * NS + s0))     * NN + t];
        const int   x1  = src[((size_t)(b * NS + s0 + 1)) * NN + t];
        const float dns = __logf(fmaf(csp, dsp, 1.0f)) / __logf(fmaf(csp, 180.0f, 1.0f));
        const float dnt = __logf(fmaf(ctp, dtp, 1.0f)) / __logf(fmaf(ctp, 365.0f, 1.0f));
        float bias_sp = 0.f, bias_tp = 0.f;
        #pragma unroll
        for (int j = 0; j < FH; ++j) {
            const float zs = dns * sp_w1[j];   // uniform addr -> scalar load
            bias_sp += (zs / (1.0f + __expf(-zs))) * sp_w2[j];
            const float zt = dnt * tp_w1[j];
            bias_tp += (zt / (1.0f + __expf(-zt))) * tp_w2[j];
        }
        const float e = __expf(bias_sp + bias_tp);
        sE[t]   = e;
        sLab[t] = lab;
        sEx0[t] = x0 ? e : 0.f;
        sEx1[t] = x1 ? e : 0.f;
    }
    __syncthreads();

    // ---- T + Bs0 + Bs1 in one scan (4 threads/cluster, n = 4i|q broadcast) ----
    {
        const int c = t >> 2, q = t & 3;
        float tS = 0.f, b0 = 0.f, b1 = 0.f;
        #pragma unroll
        for (int i = 0; i < 32; ++i) {
            const int n = (i << 2) | q;
            const bool m = (sLab[n] == c);
            tS += m ? sE[n]   : 0.f;
            b0 += m ? sEx0[n] : 0.f;
            b1 += m ? sEx1[n] : 0.f;
        }
        tS += __shfl_xor(tS, 1); tS += __shfl_xor(tS, 2);
        b0 += __shfl_xor(b0, 1); b0 += __shfl_xor(b0, 2);
        b1 += __shfl_xor(b1, 1); b1 += __shfl_xor(b1, 2);
        float p0 = 0.f, p1 = 0.f, hm = 0.f;
        if (tS > 0.f) {
            hm = 1.f;
            const float ew = __expf(attn_w[q]);  // head h == q
            p0 = (b0 * ew) / ((tS - b0) + b0 * ew);
            p1 = (b1 * ew) / ((tS - b1) + b1 * ew);
        }
        sPa[c][q] = p0;
        sPb[c][q] = p1;
        if (q == 0) sHm[c] = hm;
    }
    __syncthreads();

    // ---- stores: 2 s-values x 16 clusters, float4 NT per thread ----
    float* orow0 = out + ((size_t)(b * NS + s0)) * (NC * HID);
    #pragma unroll
    for (int ss = 0; ss < 2; ++ss) {
        float* orow = orow0 + (size_t)ss * (NC * HID);
        #pragma unroll
        for (int ci = 0; ci < 16; ++ci) {
            const int c = ci * 4 + crow;
            const float* P = ss ? sPb[c] : sPa[c];
            const float p0 = P[0], p1 = P[1], p2 = P[2], p3 = P[3];
            const float hm = sHm[c];
            f32x4 val;
            #pragma unroll
            for (int i = 0; i < 4; ++i) {
                float v = c0v[i];
                v = fmaf(p0, wrow[i][0], v);
                v = fmaf(p1, wrow[i][1], v);
                v = fmaf(p2, wrow[i][2], v);
                val[i] = fmaf(p3, wrow[i][3], v) * hm;
            }
            __builtin_nontemporal_store(val, reinterpret_cast<f32x4*>(orow + (size_t)c * HID + o0));
        }
    }
}

extern "C" void kernel_launch(void* const* d_in, const int* in_sizes, int n_in,
                              void* d_out, int out_size, void* d_ws, size_t ws_size,
                              hipStream_t stream) {
    const int*   src    = (const int*)d_in[0];
    const int*   labels = (const int*)d_in[1];
    const float* sp_d   = (const float*)d_in[2];
    const float* tp_d   = (const float*)d_in[3];
    // d_in[4] = num_clusters (fixed 64)
    const float* c_sp   = (const float*)d_in[5];
    const float* sp_w1  = (const float*)d_in[6];
    const float* sp_w2  = (const float*)d_in[7];
    const float* c_tp   = (const float*)d_in[8];
    const float* tp_w1  = (const float*)d_in[9];
    const float* tp_w2  = (const float*)d_in[10];
    const float* attn_w = (const float*)d_in[11];
    // d_in[12] = attn_b: cancels in softmax over n — unused
    const float* val_w  = (const float*)d_in[13];
    const float* val_b  = (const float*)d_in[14];
    const float* ffn_w  = (const float*)d_in[15];
    const float* ffn_b  = (const float*)d_in[16];
    float* ws = (float*)d_ws;
    float* out = (float*)d_out;

    fold_kernel<<<1, 256, 0, stream>>>(val_w, val_b, ffn_w, ffn_b, ws);
    out_kernel<<<NB * NS / 2, 256, 0, stream>>>(src, labels, sp_d, tp_d,
                                                c_sp, sp_w1, sp_w2,
                                                c_tp, tp_w1, tp_w2,
                                                attn_w, ws, out);
}

// Round 6
// 39.589 us; speedup vs baseline: 1.0074x; 1.0074x over previous
//
#include <hip/hip_runtime.h>
#include <hip/hip_bf16.h>

#define NB 8
#define NS 256
#define NN 128
#define NC 64
#define NH 4
#define AH 128
#define HID 256
#define FH 32

typedef float f32x4 __attribute__((ext_vector_type(4)));

// ws float layout:
// [1536, 1792)   const0[o] = ffn_b[o] + sum_k ffn_w[o][k]*val_b[k]
// [1792, 2816)   W[o][h]  = sum_d ffn_w[o][h*32+d]*val_w[h*32+d]

// 32 blocks x 256 threads; block owns 8 contiguous rows of ffn_w (4 KB).
// Thread t: row = blk*8 + (t>>5), lane j = t&31 covers k = 4j..4j+3.
// Wave-level loads are fully contiguous 1 KB.
__global__ __launch_bounds__(256) void fold_kernel(
    const float* __restrict__ val_w, const float* __restrict__ val_b,
    const float* __restrict__ ffn_w, const float* __restrict__ ffn_b,
    float* __restrict__ ws)
{
    const int t = threadIdx.x;
    const int j = t & 31;
    const int row = blockIdx.x * 8 + (t >> 5);
    const int k = j * 4;

    const f32x4 f  = *reinterpret_cast<const f32x4*>(ffn_w + (size_t)row * AH + k);
    const f32x4 vb = *reinterpret_cast<const f32x4*>(val_b + k);
    const f32x4 vw = *reinterpret_cast<const f32x4*>(val_w + k);

    float c0p = fmaf(f[0], vb[0], fmaf(f[1], vb[1], fmaf(f[2], vb[2], f[3] * vb[3])));
    float whp = fmaf(f[0], vw[0], fmaf(f[1], vw[1], fmaf(f[2], vw[2], f[3] * vw[3])));

    // const0: reduce over all 32 lanes of the row (stays within 32-lane half-wave)
    #pragma unroll
    for (int m = 1; m <= 16; m <<= 1) c0p += __shfl_xor(c0p, m);
    // W[h]: reduce within 8-lane groups (h = j>>3)
    #pragma unroll
    for (int m = 1; m <= 4; m <<= 1) whp += __shfl_xor(whp, m);

    if (j == 0) ws[1536 + row] = c0p + ffn_b[row];
    if ((j & 7) == 0) ws[1792 + row * NH + (j >> 3)] = whp;
}

__global__ __launch_bounds__(256) void out_kernel(
    const int* __restrict__ src,      // (B,S,N) int32, values {0,1}
    const int* __restrict__ labels,   // (B,N)
    const float* __restrict__ sp_d, const float* __restrict__ tp_d,
    const float* __restrict__ c_sp_p, const float* __restrict__ sp_w1, const float* __restrict__ sp_w2,
    const float* __restrict__ c_tp_p, const float* __restrict__ tp_w1, const float* __restrict__ tp_w2,
    const float* __restrict__ attn_w,
    const float* __restrict__ ws,
    float* __restrict__ out)          // (B,S,C,HID) float32
{
    __shared__ float sE[NN], sEx0[NN], sEx1[NN];
    __shared__ int   sLab[NN];
    __shared__ float sPa[NC][NH], sPb[NC][NH];
    __shared__ float sHm[NC];

    const int blk = blockIdx.x;      // b*128 + s_pair
    const int b  = blk >> 7;
    const int s0 = (blk & 127) * 2;
    const int t  = threadIdx.x;

    // Early fetch of per-o constants (independent of barriers below).
    const int o0 = (t & 63) * 4;     // 0..255 step 4
    const int crow = t >> 6;         // 0..3
    const f32x4 c0v = *reinterpret_cast<const f32x4*>(ws + 1536 + o0);
    f32x4 wrow[4];
    #pragma unroll
    for (int i = 0; i < 4; ++i)
        wrow[i] = *reinterpret_cast<const f32x4*>(ws + 1792 + (size_t)(o0 + i) * NH);

    // ---- FIRE bias + stage (t < 128) ----
    if (t < NN) {
        const float csp = fmaxf(c_sp_p[0], 0.0f);
        const float ctp = fmaxf(c_tp_p[0], 0.0f);
        const float dsp = sp_d[b * NN + t];
        const float dtp = tp_d[b * NN + t];
        const int   lab = labels[b * NN + t];
        const int   x0  = src[((size_t)(b * NS + s0))     * NN + t];
        const int   x1  = src[((size_t)(b * NS + s0 + 1)) * NN + t];
        const float dns = __logf(fmaf(csp, dsp, 1.0f)) / __logf(fmaf(csp, 180.0f, 1.0f));
        const float dnt = __logf(fmaf(ctp, dtp, 1.0f)) / __logf(fmaf(ctp, 365.0f, 1.0f));
        float bias_sp = 0.f, bias_tp = 0.f;
        #pragma unroll
        for (int j = 0; j < FH; ++j) {
            const float zs = dns * sp_w1[j];   // uniform addr -> scalar load
            bias_sp += (zs / (1.0f + __expf(-zs))) * sp_w2[j];
            const float zt = dnt * tp_w1[j];
            bias_tp += (zt / (1.0f + __expf(-zt))) * tp_w2[j];
        }
        const float e = __expf(bias_sp + bias_tp);
        sE[t]   = e;
        sLab[t] = lab;
        sEx0[t] = x0 ? e : 0.f;
        sEx1[t] = x1 ? e : 0.f;
    }
    __syncthreads();

    // ---- T + Bs0 + Bs1 in one scan (4 threads/cluster, n = 4i|q broadcast) ----
    {
        const int c = t >> 2, q = t & 3;
        float tS = 0.f, b0 = 0.f, b1 = 0.f;
        #pragma unroll
        for (int i = 0; i < 32; ++i) {
            const int n = (i << 2) | q;
            const bool m = (sLab[n] == c);
            tS += m ? sE[n]   : 0.f;
            b0 += m ? sEx0[n] : 0.f;
            b1 += m ? sEx1[n] : 0.f;
        }
        tS += __shfl_xor(tS, 1); tS += __shfl_xor(tS, 2);
        b0 += __shfl_xor(b0, 1); b0 += __shfl_xor(b0, 2);
        b1 += __shfl_xor(b1, 1); b1 += __shfl_xor(b1, 2);
        float p0 = 0.f, p1 = 0.f, hm = 0.f;
        if (tS > 0.f) {
            hm = 1.f;
            const float ew = __expf(attn_w[q]);  // head h == q
            p0 = (b0 * ew) / ((tS - b0) + b0 * ew);
            p1 = (b1 * ew) / ((tS - b1) + b1 * ew);
        }
        sPa[c][q] = p0;
        sPb[c][q] = p1;
        if (q == 0) sHm[c] = hm;
    }
    __syncthreads();

    // ---- stores: 2 s-values x 16 clusters, float4 NT per thread ----
    float* orow0 = out + ((size_t)(b * NS + s0)) * (NC * HID);
    #pragma unroll
    for (int ss = 0; ss < 2; ++ss) {
        float* orow = orow0 + (size_t)ss * (NC * HID);
        #pragma unroll
        for (int ci = 0; ci < 16; ++ci) {
            const int c = ci * 4 + crow;
            const float* P = ss ? sPb[c] : sPa[c];
            const float p0 = P[0], p1 = P[1], p2 = P[2], p3 = P[3];
            const float hm = sHm[c];
            f32x4 val;
            #pragma unroll
            for (int i = 0; i < 4; ++i) {
                float v = c0v[i];
                v = fmaf(p0, wrow[i][0], v);
                v = fmaf(p1, wrow[i][1], v);
                v = fmaf(p2, wrow[i][2], v);
                val[i] = fmaf(p3, wrow[i][3], v) * hm;
            }
            __builtin_nontemporal_store(val, reinterpret_cast<f32x4*>(orow + (size_t)c * HID + o0));
        }
    }
}

extern "C" void kernel_launch(void* const* d_in, const int* in_sizes, int n_in,
                              void* d_out, int out_size, void* d_ws, size_t ws_size,
                              hipStream_t stream) {
    const int*   src    = (const int*)d_in[0];
    const int*   labels = (const int*)d_in[1];
    const float* sp_d   = (const float*)d_in[2];
    const float* tp_d   = (const float*)d_in[3];
    // d_in[4] = num_clusters (fixed 64)
    const float* c_sp   = (const float*)d_in[5];
    const float* sp_w1  = (const float*)d_in[6];
    const float* sp_w2  = (const float*)d_in[7];
    const float* c_tp   = (const float*)d_in[8];
    const float* tp_w1  = (const float*)d_in[9];
    const float* tp_w2  = (const float*)d_in[10];
    const float* attn_w = (const float*)d_in[11];
    // d_in[12] = attn_b: cancels in softmax over n — unused
    const float* val_w  = (const float*)d_in[13];
    const float* val_b  = (const float*)d_in[14];
    const float* ffn_w  = (const float*)d_in[15];
    const float* ffn_b  = (const float*)d_in[16];
    float* ws = (float*)d_ws;
    float* out = (float*)d_out;

    fold_kernel<<<32, 256, 0, stream>>>(val_w, val_b, ffn_w, ffn_b, ws);
    out_kernel<<<NB * NS / 2, 256, 0, stream>>>(src, labels, sp_d, tp_d,
                                                c_sp, sp_w1, sp_w2,
                                                c_tp, tp_w1, tp_w2,
                                                attn_w, ws, out);
}

// Round 7
// 37.143 us; speedup vs baseline: 1.0737x; 1.0658x over previous
//
#include <hip/hip_runtime.h>
#include <hip/hip_bf16.h>

#define NB 8
#define NS 256
#define NN 128
#define NC 64
#define NH 4
#define AH 128
#define HID 256
#define FH 32

typedef float f32x4 __attribute__((ext_vector_type(4)));

// ws float layout:
// [1536, 1792)   const0[o] = ffn_b[o] + sum_k ffn_w[o][k]*val_b[k]
// [1792, 2816)   W[o][h]  = sum_d ffn_w[o][h*32+d]*val_w[h*32+d]

// 32 blocks x 256 threads; block owns 8 contiguous rows of ffn_w (4 KB).
// Thread t: row = blk*8 + (t>>5), lane j = t&31 covers k = 4j..4j+3.
// Wave-level loads are fully contiguous 1 KB.
__global__ __launch_bounds__(256) void fold_kernel(
    const float* __restrict__ val_w, const float* __restrict__ val_b,
    const float* __restrict__ ffn_w, const float* __restrict__ ffn_b,
    float* __restrict__ ws)
{
    const int t = threadIdx.x;
    const int j = t & 31;
    const int row = blockIdx.x * 8 + (t >> 5);
    const int k = j * 4;

    const f32x4 f  = *reinterpret_cast<const f32x4*>(ffn_w + (size_t)row * AH + k);
    const f32x4 vb = *reinterpret_cast<const f32x4*>(val_b + k);
    const f32x4 vw = *reinterpret_cast<const f32x4*>(val_w + k);

    float c0p = fmaf(f[0], vb[0], fmaf(f[1], vb[1], fmaf(f[2], vb[2], f[3] * vb[3])));
    float whp = fmaf(f[0], vw[0], fmaf(f[1], vw[1], fmaf(f[2], vw[2], f[3] * vw[3])));

    // const0: reduce over all 32 lanes of the row (stays within 32-lane half-wave)
    #pragma unroll
    for (int m = 1; m <= 16; m <<= 1) c0p += __shfl_xor(c0p, m);
    // W[h]: reduce within 8-lane groups (h = j>>3)
    #pragma unroll
    for (int m = 1; m <= 4; m <<= 1) whp += __shfl_xor(whp, m);

    if (j == 0) ws[1536 + row] = c0p + ffn_b[row];
    if ((j & 7) == 0) ws[1792 + row * NH + (j >> 3)] = whp;
}

__global__ __launch_bounds__(256) void out_kernel(
    const int* __restrict__ src,      // (B,S,N) int32, values {0,1}
    const int* __restrict__ labels,   // (B,N)
    const float* __restrict__ sp_d, const float* __restrict__ tp_d,
    const float* __restrict__ c_sp_p, const float* __restrict__ sp_w1, const float* __restrict__ sp_w2,
    const float* __restrict__ c_tp_p, const float* __restrict__ tp_w1, const float* __restrict__ tp_w2,
    const float* __restrict__ attn_w,
    const float* __restrict__ ws,
    float* __restrict__ out)          // (B,S,C,HID) float32
{
    __shared__ float sE[NN], sEx0[NN], sEx1[NN];
    __shared__ int   sLab[NN];
    __shared__ float sPa[NC][NH], sPb[NC][NH];
    __shared__ float sHm[NC];

    const int blk = blockIdx.x;      // b*128 + s_pair
    const int b  = blk >> 7;
    const int s0 = (blk & 127) * 2;
    const int t  = threadIdx.x;

    // Early fetch of per-o constants (independent of barriers below).
    const int o0 = (t & 63) * 4;     // 0..255 step 4
    const int crow = t >> 6;         // 0..3
    const f32x4 c0v = *reinterpret_cast<const f32x4*>(ws + 1536 + o0);
    f32x4 wrow[4];
    #pragma unroll
    for (int i = 0; i < 4; ++i)
        wrow[i] = *reinterpret_cast<const f32x4*>(ws + 1792 + (size_t)(o0 + i) * NH);

    // ---- FIRE bias + stage (t < 128) ----
    if (t < NN) {
        const float csp = fmaxf(c_sp_p[0], 0.0f);
        const float ctp = fmaxf(c_tp_p[0], 0.0f);
        const float dsp = sp_d[b * NN + t];
        const float dtp = tp_d[b * NN + t];
        const int   lab = labels[b * NN + t];
        const int   x0  = src[((size_t)(b * NS + s0))     * NN + t];
        const int   x1  = src[((size_t)(b * NS + s0 + 1)) * NN + t];
        const float dns = __logf(fmaf(csp, dsp, 1.0f)) / __logf(fmaf(csp, 180.0f, 1.0f));
        const float dnt = __logf(fmaf(ctp, dtp, 1.0f)) / __logf(fmaf(ctp, 365.0f, 1.0f));
        float bias_sp = 0.f, bias_tp = 0.f;
        #pragma unroll
        for (int j = 0; j < FH; ++j) {
            const float zs = dns * sp_w1[j];   // uniform addr -> scalar load
            bias_sp += (zs / (1.0f + __expf(-zs))) * sp_w2[j];
            const float zt = dnt * tp_w1[j];
            bias_tp += (zt / (1.0f + __expf(-zt))) * tp_w2[j];
        }
        const float e = __expf(bias_sp + bias_tp);
        sE[t]   = e;
        sLab[t] = lab;
        sEx0[t] = x0 ? e : 0.f;
        sEx1[t] = x1 ? e : 0.f;
    }
    __syncthreads();

    // ---- T + Bs0 + Bs1 in one scan (4 threads/cluster, n = 4i|q broadcast) ----
    {
        const int c = t >> 2, q = t & 3;
        float tS = 0.f, b0 = 0.f, b1 = 0.f;
        #pragma unroll
        for (int i = 0; i < 32; ++i) {
            const int n = (i << 2) | q;
            const bool m = (sLab[n] == c);
            tS += m ? sE[n]   : 0.f;
            b0 += m ? sEx0[n] : 0.f;
            b1 += m ? sEx1[n] : 0.f;
        }
        tS += __shfl_xor(tS, 1); tS += __shfl_xor(tS, 2);
        b0 += __shfl_xor(b0, 1); b0 += __shfl_xor(b0, 2);
        b1 += __shfl_xor(b1, 1); b1 += __shfl_xor(b1, 2);
        float p0 = 0.f, p1 = 0.f, hm = 0.f;
        if (tS > 0.f) {
            hm = 1.f;
            const float ew = __expf(attn_w[q]);  // head h == q
            p0 = (b0 * ew) / ((tS - b0) + b0 * ew);
            p1 = (b1 * ew) / ((tS - b1) + b1 * ew);
        }
        sPa[c][q] = p0;
        sPb[c][q] = p1;
        if (q == 0) sHm[c] = hm;
    }
    __syncthreads();

    // ---- stores: 2 s-values x 16 clusters, plain float4 per thread ----
    float* orow0 = out + ((size_t)(b * NS + s0)) * (NC * HID);
    #pragma unroll
    for (int ss = 0; ss < 2; ++ss) {
        float* orow = orow0 + (size_t)ss * (NC * HID);
        #pragma unroll
        for (int ci = 0; ci < 16; ++ci) {
            const int c = ci * 4 + crow;
            const float* P = ss ? sPb[c] : sPa[c];
            const float p0 = P[0], p1 = P[1], p2 = P[2], p3 = P[3];
            const float hm = sHm[c];
            f32x4 val;
            #pragma unroll
            for (int i = 0; i < 4; ++i) {
                float v = c0v[i];
                v = fmaf(p0, wrow[i][0], v);
                v = fmaf(p1, wrow[i][1], v);
                v = fmaf(p2, wrow[i][2], v);
                val[i] = fmaf(p3, wrow[i][3], v) * hm;
            }
            *reinterpret_cast<f32x4*>(orow + (size_t)c * HID + o0) = val;
        }
    }
}

extern "C" void kernel_launch(void* const* d_in, const int* in_sizes, int n_in,
                              void* d_out, int out_size, void* d_ws, size_t ws_size,
                              hipStream_t stream) {
    const int*   src    = (const int*)d_in[0];
    const int*   labels = (const int*)d_in[1];
    const float* sp_d   = (const float*)d_in[2];
    const float* tp_d   = (const float*)d_in[3];
    // d_in[4] = num_clusters (fixed 64)
    const float* c_sp   = (const float*)d_in[5];
    const float* sp_w1  = (const float*)d_in[6];
    const float* sp_w2  = (const float*)d_in[7];
    const float* c_tp   = (const float*)d_in[8];
    const float* tp_w1  = (const float*)d_in[9];
    const float* tp_w2  = (const float*)d_in[10];
    const float* attn_w = (const float*)d_in[11];
    // d_in[12] = attn_b: cancels in softmax over n — unused
    const float* val_w  = (const float*)d_in[13];
    const float* val_b  = (const float*)d_in[14];
    const float* ffn_w  = (const float*)d_in[15];
    const float* ffn_b  = (const float*)d_in[16];
    float* ws = (float*)d_ws;
    float* out = (float*)d_out;

    fold_kernel<<<32, 256, 0, stream>>>(val_w, val_b, ffn_w, ffn_b, ws);
    out_kernel<<<NB * NS / 2, 256, 0, stream>>>(src, labels, sp_d, tp_d,
                                                c_sp, sp_w1, sp_w2,
                                                c_tp, tp_w1, tp_w2,
                                                attn_w, ws, out);
}